// Round 7
// baseline (321.960 us; speedup 1.0000x reference)
//
#include <hip/hip_runtime.h>
#include <stdint.h>

#define NB     4
#define SEQ    2048
#define NH     16
#define DHD    64
#define DM     1024
#define MTOT   (NB*SEQ)     // 8192

typedef __attribute__((ext_vector_type(8))) short bf16x8;
typedef __attribute__((ext_vector_type(4))) float f32x4;

__device__ __forceinline__ short f2bf(float f) {
  uint32_t u = __float_as_uint(f);
  u = (u + 0x7FFFu + ((u >> 16) & 1u)) >> 16;   // RNE, finite inputs only
  return (short)u;
}

__device__ __forceinline__ uint32_t cvtpk(float lo, float hi) {
  uint32_t r;
  asm("v_cvt_pk_bf16_f32 %0, %1, %2" : "=v"(r) : "v"(lo), "v"(hi));
  return r;
}

__device__ __forceinline__ float exp2a(float x) {   // v_exp_f32 = 2^x
  float r;
  asm("v_exp_f32 %0, %1" : "=v"(r) : "v"(x));
  return r;
}

__device__ __forceinline__ float max3f(float a, float b, float c) {
  return fmaxf(fmaxf(a, b), c);                     // clang fuses to v_max3_f32
}

__device__ __forceinline__ f32x4 mfma16(bf16x8 a, bf16x8 b, f32x4 c) {
  return __builtin_amdgcn_mfma_f32_16x16x32_bf16(a, b, c, 0, 0, 0);
}

__device__ __forceinline__ void async16(const void* g, void* l) {
  __builtin_amdgcn_global_load_lds(
      (const __attribute__((address_space(1))) void*)g,
      (__attribute__((address_space(3))) void*)l, 16, 0, 0);
}

// ---- cast x f32 -> bf16 ----
__global__ void k_cast(const float* __restrict__ in, short* __restrict__ out, int n) {
  int i = (blockIdx.x * blockDim.x + threadIdx.x) * 8;
  if (i >= n) return;
  float4 a = *reinterpret_cast<const float4*>(in + i);
  float4 b = *reinterpret_cast<const float4*>(in + i + 4);
  bf16x8 v;
  v[0] = f2bf(a.x); v[1] = f2bf(a.y); v[2] = f2bf(a.z); v[3] = f2bf(a.w);
  v[4] = f2bf(b.x); v[5] = f2bf(b.y); v[6] = f2bf(b.z); v[7] = f2bf(b.w);
  *reinterpret_cast<bf16x8*>(out + i) = v;
}

// ---- mask -> additive float bias ----
__global__ void k_maskbias(const int* __restrict__ pm, float* __restrict__ fb, int n) {
  int i = blockIdx.x * blockDim.x + threadIdx.x;
  if (i < n) fb[i] = pm[i] ? 0.0f : -1e30f;
}

// ---- transpose+cast W [K=1024][N=1024] f32 -> Wt [N][K] bf16 ----
__global__ void k_transpose(const float* __restrict__ in, short* __restrict__ out) {
  __shared__ float tile[32][33];
  int n0 = blockIdx.x * 32, k0 = blockIdx.y * 32;
  int tx = threadIdx.x, ty = threadIdx.y;   // block (32,8)
  #pragma unroll
  for (int i = 0; i < 32; i += 8)
    tile[ty + i][tx] = in[(size_t)(k0 + ty + i) * DM + n0 + tx];
  __syncthreads();
  #pragma unroll
  for (int i = 0; i < 32; i += 8)
    out[(size_t)(n0 + ty + i) * DM + k0 + tx] = f2bf(tile[tx][ty + i]);
}

// ---- 128x128x(K=1024) bf16 MFMA GEMM, B given transposed [N][K] ----
// MODE 0: C bf16 [M][DM]  (scaled)   MODE 1: C bf16 as Vt[b][n][s]   MODE 2: C f32
template<int MODE>
__global__ void __launch_bounds__(256) k_gemm(const short* __restrict__ A,
                                              const short* __restrict__ Bt,
                                              const float* __restrict__ bias,
                                              void* __restrict__ Cv, float scale) {
  __shared__ short lA[128 * 32];
  __shared__ short lB[128 * 32];
  int lin = blockIdx.y * gridDim.x + blockIdx.x;      // 512 blocks, 512%8==0
  int s = ((lin & 7) << 6) | (lin >> 3);              // bijective XCD swizzle
  int m0 = (s & 63) * 128, n0 = (s >> 6) * 128;
  int tid = threadIdx.x, lane = tid & 63, w = tid >> 6;
  int wr = w >> 1, wc = w & 1;
  int l15 = lane & 15, lg = lane >> 4;
  f32x4 acc[4][4] = {};

  int r0 = tid >> 2, c0 = (tid & 3) * 8;
  int r1 = (tid + 256) >> 2, c1 = ((tid + 256) & 3) * 8;
  const short* ga0 = A + (size_t)(m0 + r0) * DM + c0;
  const short* ga1 = A + (size_t)(m0 + r1) * DM + c1;
  const short* gb0 = Bt + (size_t)(n0 + r0) * DM + c0;
  const short* gb1 = Bt + (size_t)(n0 + r1) * DM + c1;
  short* lA0 = lA + w * 512;
  short* lA1 = lA + 2048 + w * 512;
  short* lB0 = lB + w * 512;
  short* lB1 = lB + 2048 + w * 512;

  for (int k0 = 0; k0 < DM; k0 += 32) {
    async16(ga0 + k0, lA0);
    async16(ga1 + k0, lA1);
    async16(gb0 + k0, lB0);
    async16(gb1 + k0, lB1);
    __syncthreads();
    bf16x8 af[4], bfr[4];
    #pragma unroll
    for (int i = 0; i < 4; ++i) {
      af[i]  = *reinterpret_cast<const bf16x8*>(lA + (wr * 64 + i * 16 + l15) * 32 + lg * 8);
      bfr[i] = *reinterpret_cast<const bf16x8*>(lB + (wc * 64 + i * 16 + l15) * 32 + lg * 8);
    }
    #pragma unroll
    for (int i = 0; i < 4; ++i)
      #pragma unroll
      for (int j = 0; j < 4; ++j)
        acc[i][j] = mfma16(af[i], bfr[j], acc[i][j]);
    __syncthreads();
  }

  #pragma unroll
  for (int j = 0; j < 4; ++j) {
    int cg = n0 + wc * 64 + j * 16 + l15;
    float bv = bias[cg];
    #pragma unroll
    for (int i = 0; i < 4; ++i) {
      #pragma unroll
      for (int r = 0; r < 4; ++r) {
        int rg = m0 + wr * 64 + i * 16 + lg * 4 + r;
        float val = (acc[i][j][r] + bv) * scale;
        if (MODE == 0)
          ((short*)Cv)[(size_t)rg * DM + cg] = f2bf(val);
        else if (MODE == 1)
          ((short*)Cv)[((size_t)((rg >> 11) * DM + cg)) * SEQ + (rg & 2047)] = f2bf(val);
        else
          ((float*)Cv)[(size_t)rg * DM + cg] = val;
      }
    }
  }
}

// ---- softmax for one 16-q half (S^T regs -> P strip in LDS) ----
__device__ __forceinline__ void softmax_half(const f32x4* st, const float4* fb4,
                                             float c2, float d0, int lg,
                                             float& mrun, float& ssum,
                                             f32x4* acc, uint32_t* wb) {
  float l[16];
  #pragma unroll
  for (int t = 0; t < 4; ++t) {
    l[t * 4 + 0] = fmaf(-c2, fabsf(d0 - (float)(t * 16 + 0)), st[t][0] + fb4[t].x);
    l[t * 4 + 1] = fmaf(-c2, fabsf(d0 - (float)(t * 16 + 1)), st[t][1] + fb4[t].y);
    l[t * 4 + 2] = fmaf(-c2, fabsf(d0 - (float)(t * 16 + 2)), st[t][2] + fb4[t].z);
    l[t * 4 + 3] = fmaf(-c2, fabsf(d0 - (float)(t * 16 + 3)), st[t][3] + fb4[t].w);
  }
  float ma = max3f(l[0], l[1], l[2]);
  float mb = max3f(l[3], l[4], l[5]);
  float mc = max3f(l[6], l[7], l[8]);
  float md = max3f(l[9], l[10], l[11]);
  float me = max3f(l[12], l[13], l[14]);
  float tmax = fmaxf(max3f(ma, mb, mc), max3f(md, me, l[15]));
  tmax = fmaxf(tmax, __shfl_xor(tmax, 16));
  tmax = fmaxf(tmax, __shfl_xor(tmax, 32));

  // defer-max: skip rescale while max growth < 8 (2^8 headroom in bf16 P)
  if (!__all(tmax <= mrun + 8.0f)) {
    float mn = fmaxf(mrun, tmax);
    float fsc = exp2a(mrun - mn);
    mrun = mn;
    ssum *= fsc;
    #pragma unroll
    for (int td = 0; td < 4; ++td) acc[td] *= fsc;
  }

  float p[16];
  #pragma unroll
  for (int i = 0; i < 16; ++i) p[i] = exp2a(l[i] - mrun);
  float a0 = p[0] + p[1],  a1 = p[2] + p[3],  a2 = p[4] + p[5],  a3 = p[6] + p[7];
  float a4 = p[8] + p[9],  a5 = p[10] + p[11], a6 = p[12] + p[13], a7 = p[14] + p[15];
  float b0 = a0 + a1, b1 = a2 + a3, b2 = a4 + a5, b3 = a6 + a7;
  float rs = (b0 + b1) + (b2 + b3);
  rs += __shfl_xor(rs, 16);
  rs += __shfl_xor(rs, 32);
  ssum += rs;

  #pragma unroll
  for (int t = 0; t < 4; ++t) {
    uint2 wv = { cvtpk(p[t * 4 + 0], p[t * 4 + 1]), cvtpk(p[t * 4 + 2], p[t * 4 + 3]) };
    *reinterpret_cast<uint2*>(wb + t * 8 + lg * 2) = wv;
  }
}

// ---- flash attention, swapped-operand, QBLK=32/wave, split-barrier pipeline ----
// 1-D grid 1024 (XCD-affinity: head-group pinned per XCD -> K/V L2-local).
// Per tile: vmcnt(2)+bar (K landed) -> QK^T -> bar (lK free) -> issue K(t+1)
// -> softmax -> lgkmcnt(0)+vmcnt(2)+bar (V landed) -> PV -> bar (lV free) ->
// issue V(t+1). Counted vmcnt (T4): never drains the newer stage pair, so
// each stage has ~half a tile of compute to fly. LDS 35.8 KB -> 4 blocks/CU.
__global__ void __launch_bounds__(256) k_attn(const short* __restrict__ Q,
                                              const short* __restrict__ Kb,
                                              const short* __restrict__ Vt,
                                              const float* __restrict__ fbias,
                                              short* __restrict__ O) {
  __shared__ short lK[64 * 64];              // 8 KB
  __shared__ short lV[64 * 64];              // 8 KB
  __shared__ uint32_t pbuf[4 * 2 * 16 * 38]; // 19 KB strips (stride 38: 2-way banks)
  // unmap: XCD = g&7 = bh&7; qt = (g>>3)&15; bh = (g&7) + 8*(g>>7)
  int g = blockIdx.x;
  int qt = (g >> 3) & 15;
  int bh = (g & 7) + ((g >> 7) << 3);
  int b = bh >> 4, h = bh & 15;
  int tid = threadIdx.x, lane = tid & 63, w = tid >> 6;
  int l15 = lane & 15, lg = lane >> 4;
  int q0 = qt * 128 + w * 32;
  // log2 domain: c2 = slope/sqrt(64) * log2e
  float c2 = exp2f(-0.5f * (float)(h + 1)) * 0.125f * 1.44269504f;

  // Q as B-fragments; Q pre-scaled by log2e/8 in GEMM epilogue
  const short* qpA = Q + (size_t)(b * SEQ + q0 + l15) * DM + h * DHD + lg * 8;
  bf16x8 bqA0 = *reinterpret_cast<const bf16x8*>(qpA);
  bf16x8 bqA1 = *reinterpret_cast<const bf16x8*>(qpA + 32);
  const short* qpB = qpA + (size_t)16 * DM;
  bf16x8 bqB0 = *reinterpret_cast<const bf16x8*>(qpB);
  bf16x8 bqB1 = *reinterpret_cast<const bf16x8*>(qpB + 32);

  // staging: thread -> (row, chunk); global src pre-swizzled, LDS dest linear
  int srow0 = w * 8 + (lane >> 3);           // issue0 rows 0..31
  int srow1 = srow0 + 32;                    // issue1 rows 32..63
  int sc0 = (lane & 7) ^ (srow0 & 7);
  int sc1 = (lane & 7) ^ (srow1 & 7);
  const short* kg0 = Kb + (size_t)(b * SEQ + srow0) * DM + h * DHD + sc0 * 8;
  const short* kg1 = Kb + (size_t)(b * SEQ + srow1) * DM + h * DHD + sc1 * 8;
  const short* vg0 = Vt + ((size_t)bh * DHD + srow0) * SEQ + sc0 * 8;
  const short* vg1 = Vt + ((size_t)bh * DHD + srow1) * SEQ + sc1 * 8;
  short* dK0 = lK + w * 512;
  short* dK1 = lK + 2048 + w * 512;
  short* dV0 = lV + w * 512;
  short* dV1 = lV + 2048 + w * 512;

  const float* fb = fbias + b * SEQ;
  uint32_t* wbA = pbuf + w * 1216 + l15 * 38;
  uint32_t* wbB = wbA + 608;
  int sw = l15 & 7;

  float mrunA = -1e30f, ssumA = 0.0f, mrunB = -1e30f, ssumB = 0.0f;
  f32x4 accA[4] = {}, accB[4] = {};
  float d0A = (float)(q0 + l15) - (float)(lg * 4);
  float d0B = d0A + 16.0f;

  // prologue: issue K(0) then V(0)
  async16(kg0, dK0);
  async16(kg1, dK1);
  kg0 += (size_t)64 * DM; kg1 += (size_t)64 * DM;
  async16(vg0, dV0);
  async16(vg1, dV1);
  vg0 += 64; vg1 += 64;

  for (int kt = 0; kt < SEQ; kt += 64) {
    bool more = (kt + 64) < SEQ;

    asm volatile("s_waitcnt vmcnt(2)" ::: "memory");  // own K(t) landed (V(t) in flight)
    __builtin_amdgcn_s_barrier();                     // everyone's K(t) landed
    __builtin_amdgcn_sched_barrier(0);

    float4 fb4[4];
    #pragma unroll
    for (int t = 0; t < 4; ++t)
      fb4[t] = *reinterpret_cast<const float4*>(fb + kt + t * 16 + lg * 4);

    // QK^T both halves: K fragments read ONCE, used 2x
    f32x4 stA[4], stB[4];
    __builtin_amdgcn_s_setprio(1);
    #pragma unroll
    for (int t = 0; t < 4; ++t) {
      int row = t * 16 + l15;
      bf16x8 k0 = *reinterpret_cast<const bf16x8*>(lK + row * 64 + (lg ^ sw) * 8);
      bf16x8 k1 = *reinterpret_cast<const bf16x8*>(lK + row * 64 + ((lg + 4) ^ sw) * 8);
      f32x4 zA = {};
      zA = mfma16(k0, bqA0, zA);
      stA[t] = mfma16(k1, bqA1, zA);
      f32x4 zB = {};
      zB = mfma16(k0, bqB0, zB);
      stB[t] = mfma16(k1, bqB1, zB);
    }
    __builtin_amdgcn_s_setprio(0);

    __builtin_amdgcn_s_barrier();                     // all waves done reading lK
    __builtin_amdgcn_sched_barrier(0);
    if (more) {                                       // stage K(t+1); flies under softmax+PV
      async16(kg0, dK0);
      async16(kg1, dK1);
      kg0 += (size_t)64 * DM; kg1 += (size_t)64 * DM;
    }

    softmax_half(stA, fb4, c2, d0A, lg, mrunA, ssumA, accA, wbA);
    softmax_half(stB, fb4, c2, d0B, lg, mrunB, ssumB, accB, wbB);

    asm volatile("s_waitcnt lgkmcnt(0)" ::: "memory"); // strips written
    if (more)
      asm volatile("s_waitcnt vmcnt(2)" ::: "memory"); // own V(t) landed (K(t+1) in flight)
    else
      asm volatile("s_waitcnt vmcnt(0)" ::: "memory");
    __builtin_amdgcn_s_barrier();                      // everyone's V(t) landed
    __builtin_amdgcn_sched_barrier(0);

    // PV both halves: V fragments read ONCE, used 2x
    __builtin_amdgcn_s_setprio(1);
    #pragma unroll
    for (int ks = 0; ks < 2; ++ks) {
      int t = ks * 2 + (lg >> 1);
      bf16x8 pfA = *reinterpret_cast<const bf16x8*>(wbA + t * 8 + (lg & 1) * 4);
      bf16x8 pfB = *reinterpret_cast<const bf16x8*>(wbB + t * 8 + (lg & 1) * 4);
      #pragma unroll
      for (int td = 0; td < 4; ++td) {
        int row = td * 16 + l15;
        bf16x8 vf = *reinterpret_cast<const bf16x8*>(lV + row * 64 + ((ks * 4 + lg) ^ sw) * 8);
        accA[td] = mfma16(vf, pfA, accA[td]);
        accB[td] = mfma16(vf, pfB, accB[td]);
      }
    }
    __builtin_amdgcn_s_setprio(0);
    d0A -= 64.0f; d0B -= 64.0f;

    __builtin_amdgcn_s_barrier();                      // all waves done reading lV
    __builtin_amdgcn_sched_barrier(0);
    if (more) {                                        // stage V(t+1); flies under next QK^T
      async16(vg0, dV0);
      async16(vg1, dV1);
      vg0 += 64; vg1 += 64;
    }
  }

  float invA = 1.0f / ssumA;
  float invB = 1.0f / ssumB;
  short* opA = O + (size_t)(b * SEQ + q0 + l15) * DM + h * DHD;
  short* opB = opA + (size_t)16 * DM;
  #pragma unroll
  for (int td = 0; td < 4; ++td) {
    uint2 wvA = { cvtpk(accA[td][0] * invA, accA[td][1] * invA),
                  cvtpk(accA[td][2] * invA, accA[td][3] * invA) };
    *reinterpret_cast<uint2*>(opA + td * 16 + lg * 4) = wvA;
    uint2 wvB = { cvtpk(accB[td][0] * invB, accB[td][1] * invB),
                  cvtpk(accB[td][2] * invB, accB[td][3] * invB) };
    *reinterpret_cast<uint2*>(opB + td * 16 + lg * 4) = wvB;
  }
}

extern "C" void kernel_launch(void* const* d_in, const int* in_sizes, int n_in,
                              void* d_out, int out_size, void* d_ws, size_t ws_size,
                              hipStream_t stream) {
  const float* x  = (const float*)d_in[0];
  const float* Wq = (const float*)d_in[1];
  const float* bq = (const float*)d_in[2];
  const float* Wk = (const float*)d_in[3];
  const float* bk = (const float*)d_in[4];
  const float* Wv = (const float*)d_in[5];
  const float* bv = (const float*)d_in[6];
  const float* Wo = (const float*)d_in[7];
  const float* bo = (const float*)d_in[8];
  const int*   pm = (const int*)d_in[9];

  char* ws = (char*)d_ws;
  const size_t MB = 1ull << 20;
  short* xb  = (short*)(ws + 0 * MB);
  short* q   = (short*)(ws + 16 * MB);
  short* k   = (short*)(ws + 32 * MB);
  short* vt  = (short*)(ws + 48 * MB);
  short* ob  = (short*)(ws + 64 * MB);
  short* wqt = (short*)(ws + 80 * MB);
  short* wkt = (short*)(ws + 82 * MB);
  short* wvt = (short*)(ws + 84 * MB);
  short* wot = (short*)(ws + 86 * MB);
  float* fbias = (float*)(ws + 88 * MB);

  k_cast<<<dim3(MTOT * DM / 8 / 256), dim3(256), 0, stream>>>(x, xb, MTOT * DM);
  k_maskbias<<<dim3(MTOT / 256), dim3(256), 0, stream>>>(pm, fbias, MTOT);
  k_transpose<<<dim3(32, 32), dim3(32, 8), 0, stream>>>(Wq, wqt);
  k_transpose<<<dim3(32, 32), dim3(32, 8), 0, stream>>>(Wk, wkt);
  k_transpose<<<dim3(32, 32), dim3(32, 8), 0, stream>>>(Wv, wvt);
  k_transpose<<<dim3(32, 32), dim3(32, 8), 0, stream>>>(Wo, wot);
  // Q pre-scaled by log2e/8 (log2-domain softmax)
  k_gemm<0><<<dim3(64, 8), dim3(256), 0, stream>>>(xb, wqt, bq, q, 0.125f * 1.44269504f);
  k_gemm<0><<<dim3(64, 8), dim3(256), 0, stream>>>(xb, wkt, bk, k, 1.0f);
  k_gemm<1><<<dim3(64, 8), dim3(256), 0, stream>>>(xb, wvt, bv, vt, 1.0f);
  k_attn<<<dim3(SEQ / 128 * NB * NH), dim3(256), 0, stream>>>(q, k, vt, fbias, ob);
  k_gemm<2><<<dim3(64, 8), dim3(256), 0, stream>>>(ob, wot, bo, d_out, 1.0f);
}

// Round 8
// 259.998 us; speedup vs baseline: 1.2383x; 1.2383x over previous
//
#include <hip/hip_runtime.h>
#include <stdint.h>

#define NB     4
#define SEQ    2048
#define NH     16
#define DHD    64
#define DM     1024
#define MTOT   (NB*SEQ)     // 8192
#define HSZ    (SEQ*DHD)    // 131072 shorts per (b,h) in K'/V'

typedef __attribute__((ext_vector_type(8))) short bf16x8;
typedef __attribute__((ext_vector_type(4))) float f32x4;

__device__ __forceinline__ short f2bf(float f) {
  uint32_t u = __float_as_uint(f);
  u = (u + 0x7FFFu + ((u >> 16) & 1u)) >> 16;   // RNE, finite inputs only
  return (short)u;
}

__device__ __forceinline__ uint32_t cvtpk(float lo, float hi) {
  uint32_t r;
  asm("v_cvt_pk_bf16_f32 %0, %1, %2" : "=v"(r) : "v"(lo), "v"(hi));
  return r;
}

__device__ __forceinline__ float exp2a(float x) {   // v_exp_f32 = 2^x
  float r;
  asm("v_exp_f32 %0, %1" : "=v"(r) : "v"(x));
  return r;
}

__device__ __forceinline__ float max3f(float a, float b, float c) {
  return fmaxf(fmaxf(a, b), c);                     // clang fuses to v_max3_f32
}

__device__ __forceinline__ f32x4 mfma16(bf16x8 a, bf16x8 b, f32x4 c) {
  return __builtin_amdgcn_mfma_f32_16x16x32_bf16(a, b, c, 0, 0, 0);
}

__device__ __forceinline__ void async16(const void* g, void* l) {
  __builtin_amdgcn_global_load_lds(
      (const __attribute__((address_space(1))) void*)g,
      (__attribute__((address_space(3))) void*)l, 16, 0, 0);
}

// ---- cast x f32 -> bf16 ----
__global__ void k_cast(const float* __restrict__ in, short* __restrict__ out, int n) {
  int i = (blockIdx.x * blockDim.x + threadIdx.x) * 8;
  if (i >= n) return;
  float4 a = *reinterpret_cast<const float4*>(in + i);
  float4 b = *reinterpret_cast<const float4*>(in + i + 4);
  bf16x8 v;
  v[0] = f2bf(a.x); v[1] = f2bf(a.y); v[2] = f2bf(a.z); v[3] = f2bf(a.w);
  v[4] = f2bf(b.x); v[5] = f2bf(b.y); v[6] = f2bf(b.z); v[7] = f2bf(b.w);
  *reinterpret_cast<bf16x8*>(out + i) = v;
}

// ---- mask -> additive float bias ----
__global__ void k_maskbias(const int* __restrict__ pm, float* __restrict__ fb, int n) {
  int i = blockIdx.x * blockDim.x + threadIdx.x;
  if (i < n) fb[i] = pm[i] ? 0.0f : -1e30f;
}

// ---- transpose+cast W [K=1024][N=1024] f32 -> Wt [N][K] bf16 ----
__global__ void k_transpose(const float* __restrict__ in, short* __restrict__ out) {
  __shared__ float tile[32][33];
  int n0 = blockIdx.x * 32, k0 = blockIdx.y * 32;
  int tx = threadIdx.x, ty = threadIdx.y;   // block (32,8)
  #pragma unroll
  for (int i = 0; i < 32; i += 8)
    tile[ty + i][tx] = in[(size_t)(k0 + ty + i) * DM + n0 + tx];
  __syncthreads();
  #pragma unroll
  for (int i = 0; i < 32; i += 8)
    out[(size_t)(n0 + ty + i) * DM + k0 + tx] = f2bf(tile[tx][ty + i]);
}

// ---- 128x128x(K=1024) bf16 MFMA GEMM, B given transposed [N][K] ----
// MODE 0: C bf16 [M][DM] (scaled)           (Q)
// MODE 1: C bf16 V' fragment-ready           (V)
// MODE 2: C f32 [M][DM]                      (final out)
// MODE 3: C bf16 K' fragment-ready           (K)
// K'[bh][rt=s>>4] block: 128 vec8 = (dh>>3)*16 + (s&15), elem dh&7
// V'[bh][t64=s>>6] block: 512 vec8 = ((dh>>4)*8 + ((s>>3)&7))*16 + (dh&15), elem s&7
template<int MODE>
__global__ void __launch_bounds__(256) k_gemm(const short* __restrict__ A,
                                              const short* __restrict__ Bt,
                                              const float* __restrict__ bias,
                                              void* __restrict__ Cv, float scale) {
  __shared__ short lA[128 * 32];
  __shared__ short lB[128 * 32];
  int lin = blockIdx.y * gridDim.x + blockIdx.x;      // 512 blocks, 512%8==0
  int s = ((lin & 7) << 6) | (lin >> 3);              // bijective XCD swizzle
  int m0 = (s & 63) * 128, n0 = (s >> 6) * 128;
  int tid = threadIdx.x, lane = tid & 63, w = tid >> 6;
  int wr = w >> 1, wc = w & 1;
  int l15 = lane & 15, lg = lane >> 4;
  f32x4 acc[4][4] = {};

  int r0 = tid >> 2, c0 = (tid & 3) * 8;
  int r1 = (tid + 256) >> 2, c1 = ((tid + 256) & 3) * 8;
  const short* ga0 = A + (size_t)(m0 + r0) * DM + c0;
  const short* ga1 = A + (size_t)(m0 + r1) * DM + c1;
  const short* gb0 = Bt + (size_t)(n0 + r0) * DM + c0;
  const short* gb1 = Bt + (size_t)(n0 + r1) * DM + c1;
  short* lA0 = lA + w * 512;
  short* lA1 = lA + 2048 + w * 512;
  short* lB0 = lB + w * 512;
  short* lB1 = lB + 2048 + w * 512;

  for (int k0 = 0; k0 < DM; k0 += 32) {
    async16(ga0 + k0, lA0);
    async16(ga1 + k0, lA1);
    async16(gb0 + k0, lB0);
    async16(gb1 + k0, lB1);
    __syncthreads();
    bf16x8 af[4], bfr[4];
    #pragma unroll
    for (int i = 0; i < 4; ++i) {
      af[i]  = *reinterpret_cast<const bf16x8*>(lA + (wr * 64 + i * 16 + l15) * 32 + lg * 8);
      bfr[i] = *reinterpret_cast<const bf16x8*>(lB + (wc * 64 + i * 16 + l15) * 32 + lg * 8);
    }
    #pragma unroll
    for (int i = 0; i < 4; ++i)
      #pragma unroll
      for (int j = 0; j < 4; ++j)
        acc[i][j] = mfma16(af[i], bfr[j], acc[i][j]);
    __syncthreads();
  }

  #pragma unroll
  for (int j = 0; j < 4; ++j) {
    int cg = n0 + wc * 64 + j * 16 + l15;
    float bv = bias[cg];
    #pragma unroll
    for (int i = 0; i < 4; ++i) {
      #pragma unroll
      for (int r = 0; r < 4; ++r) {
        int rg = m0 + wr * 64 + i * 16 + lg * 4 + r;
        float val = (acc[i][j][r] + bv) * scale;
        if (MODE == 0) {
          ((short*)Cv)[(size_t)rg * DM + cg] = f2bf(val);
        } else if (MODE == 1) {
          int bh2 = ((rg >> 11) << 4) | (cg >> 6);
          int dh = cg & 63, sl = rg & 2047;
          size_t fi = (size_t)bh2 * HSZ + (size_t)(sl >> 6) * 4096
                    + (size_t)((((dh >> 4) * 8 + ((sl >> 3) & 7)) * 16 + (dh & 15)) * 8 + (sl & 7));
          ((short*)Cv)[fi] = f2bf(val);
        } else if (MODE == 3) {
          int bh2 = ((rg >> 11) << 4) | (cg >> 6);
          int dh = cg & 63, sl = rg & 2047;
          size_t fi = (size_t)bh2 * HSZ + (size_t)(sl >> 4) * 1024
                    + (size_t)((((dh >> 3) * 16 + (sl & 15)) * 8) + (dh & 7));
          ((short*)Cv)[fi] = f2bf(val);
        } else {
          ((float*)Cv)[(size_t)rg * DM + cg] = val;
        }
      }
    }
  }
}

// ---- softmax for one 16-q half (S^T regs -> P strip in LDS) ----
__device__ __forceinline__ void softmax_half(const f32x4* st, const float4* fb4,
                                             float c2, float d0, int lg,
                                             float& mrun, float& ssum,
                                             f32x4* acc, uint32_t* wb) {
  float l[16];
  #pragma unroll
  for (int t = 0; t < 4; ++t) {
    l[t * 4 + 0] = fmaf(-c2, fabsf(d0 - (float)(t * 16 + 0)), st[t][0] + fb4[t].x);
    l[t * 4 + 1] = fmaf(-c2, fabsf(d0 - (float)(t * 16 + 1)), st[t][1] + fb4[t].y);
    l[t * 4 + 2] = fmaf(-c2, fabsf(d0 - (float)(t * 16 + 2)), st[t][2] + fb4[t].z);
    l[t * 4 + 3] = fmaf(-c2, fabsf(d0 - (float)(t * 16 + 3)), st[t][3] + fb4[t].w);
  }
  float ma = max3f(l[0], l[1], l[2]);
  float mb = max3f(l[3], l[4], l[5]);
  float mc = max3f(l[6], l[7], l[8]);
  float md = max3f(l[9], l[10], l[11]);
  float me = max3f(l[12], l[13], l[14]);
  float tmax = fmaxf(max3f(ma, mb, mc), max3f(md, me, l[15]));
  tmax = fmaxf(tmax, __shfl_xor(tmax, 16));
  tmax = fmaxf(tmax, __shfl_xor(tmax, 32));

  // defer-max: skip rescale while max growth < 8 (2^8 headroom in bf16 P)
  if (!__all(tmax <= mrun + 8.0f)) {
    float mn = fmaxf(mrun, tmax);
    float fsc = exp2a(mrun - mn);
    mrun = mn;
    ssum *= fsc;
    #pragma unroll
    for (int td = 0; td < 4; ++td) acc[td] *= fsc;
  }

  float p[16];
  #pragma unroll
  for (int i = 0; i < 16; ++i) p[i] = exp2a(l[i] - mrun);
  float a0 = p[0] + p[1],  a1 = p[2] + p[3],  a2 = p[4] + p[5],  a3 = p[6] + p[7];
  float a4 = p[8] + p[9],  a5 = p[10] + p[11], a6 = p[12] + p[13], a7 = p[14] + p[15];
  float b0 = a0 + a1, b1 = a2 + a3, b2 = a4 + a5, b3 = a6 + a7;
  float rs = (b0 + b1) + (b2 + b3);
  rs += __shfl_xor(rs, 16);
  rs += __shfl_xor(rs, 32);
  ssum += rs;

  #pragma unroll
  for (int t = 0; t < 4; ++t) {
    uint2 wv = { cvtpk(p[t * 4 + 0], p[t * 4 + 1]), cvtpk(p[t * 4 + 2], p[t * 4 + 3]) };
    *reinterpret_cast<uint2*>(wb + t * 8 + lg * 2) = wv;
  }
}

// ---- flash attention: barrier-free, 1 wave/block, fragment-direct K'/V' ----
// K'/V' are packed by the GEMM epilogues so each fragment is a fully
// coalesced global_load_dwordx4 (base + lane*16B) straight from L2.
// No K/V LDS, no __syncthreads; only the wave-private P strip uses LDS
// (lgkmcnt(0)+sched_barrier, rule #18). XCD-affinity grid keeps each
// head's 512 KB of K'/V' resident in one XCD's L2.
__global__ void __launch_bounds__(64, 3) k_attn(const short* __restrict__ Q,
                                                const short* __restrict__ KF,
                                                const short* __restrict__ VF,
                                                const float* __restrict__ fbias,
                                                short* __restrict__ O) {
  __shared__ uint32_t pbuf[2 * 16 * 38];     // 4.9 KB strips (stride 38)
  // unmap: XCD = g&7 = bh&7; qb = (g>>3)&63; bh = (g&7) + 8*(g>>9)
  int g = blockIdx.x;
  int qb = (g >> 3) & 63;
  int bh = (g & 7) + ((g >> 9) << 3);
  int b = bh >> 4, h = bh & 15;
  int lane = threadIdx.x;
  int l15 = lane & 15, lg = lane >> 4;
  int q0 = qb * 32;
  // log2 domain: c2 = slope/sqrt(64) * log2e
  float c2 = exp2f(-0.5f * (float)(h + 1)) * 0.125f * 1.44269504f;

  // Q as B-fragments; Q pre-scaled by log2e/8 in GEMM epilogue
  const short* qpA = Q + (size_t)(b * SEQ + q0 + l15) * DM + h * DHD + lg * 8;
  bf16x8 bqA0 = *reinterpret_cast<const bf16x8*>(qpA);
  bf16x8 bqA1 = *reinterpret_cast<const bf16x8*>(qpA + 32);
  const short* qpB = qpA + (size_t)16 * DM;
  bf16x8 bqB0 = *reinterpret_cast<const bf16x8*>(qpB);
  bf16x8 bqB1 = *reinterpret_cast<const bf16x8*>(qpB + 32);

  const short* kbase = KF + (size_t)bh * HSZ + lane * 8;
  const short* vbase = VF + (size_t)bh * HSZ + lane * 8;
  const float* fb = fbias + b * SEQ;
  uint32_t* wbA = pbuf + l15 * 38;
  uint32_t* wbB = pbuf + 608 + l15 * 38;

  float mrunA = -1e30f, ssumA = 0.0f, mrunB = -1e30f, ssumB = 0.0f;
  f32x4 accA[4] = {}, accB[4] = {};
  float d0A = (float)(q0 + l15) - (float)(lg * 4);
  float d0B = d0A + 16.0f;

  for (int kt = 0; kt < SEQ; kt += 64) {
    // issue order matters (in-order vmcnt retirement):
    // fb4 (retire first) -> ka (QK^T waits these, va still flying) -> va
    float4 fb4[4];
    #pragma unroll
    for (int t = 0; t < 4; ++t)
      fb4[t] = *reinterpret_cast<const float4*>(fb + kt + t * 16 + lg * 4);

    const short* kp = kbase + (size_t)(kt >> 4) * 1024;
    bf16x8 ka[4][2];
    #pragma unroll
    for (int t = 0; t < 4; ++t) {
      ka[t][0] = *reinterpret_cast<const bf16x8*>(kp + t * 1024);
      ka[t][1] = *reinterpret_cast<const bf16x8*>(kp + t * 1024 + 512);
    }
    const short* vp = vbase + (size_t)(kt >> 6) * 4096;
    bf16x8 va[4][2];
    #pragma unroll
    for (int td = 0; td < 4; ++td) {
      va[td][0] = *reinterpret_cast<const bf16x8*>(vp + (td * 8 + 0) * 128);
      va[td][1] = *reinterpret_cast<const bf16x8*>(vp + (td * 8 + 4) * 128);
    }

    // QK^T both halves (K fragments in regs, used 2x)
    f32x4 stA[4], stB[4];
    __builtin_amdgcn_s_setprio(1);
    #pragma unroll
    for (int t = 0; t < 4; ++t) {
      f32x4 zA = {};
      zA = mfma16(ka[t][0], bqA0, zA);
      stA[t] = mfma16(ka[t][1], bqA1, zA);
      f32x4 zB = {};
      zB = mfma16(ka[t][0], bqB0, zB);
      stB[t] = mfma16(ka[t][1], bqB1, zB);
    }
    __builtin_amdgcn_s_setprio(0);

    softmax_half(stA, fb4, c2, d0A, lg, mrunA, ssumA, accA, wbA);
    softmax_half(stB, fb4, c2, d0B, lg, mrunB, ssumB, accB, wbB);

    asm volatile("s_waitcnt lgkmcnt(0)" ::: "memory");  // strips written
    __builtin_amdgcn_sched_barrier(0);

    // PV both halves (V fragments in regs, used 2x)
    __builtin_amdgcn_s_setprio(1);
    #pragma unroll
    for (int ks = 0; ks < 2; ++ks) {
      int t = ks * 2 + (lg >> 1);
      bf16x8 pfA = *reinterpret_cast<const bf16x8*>(wbA + t * 8 + (lg & 1) * 4);
      bf16x8 pfB = *reinterpret_cast<const bf16x8*>(wbB + t * 8 + (lg & 1) * 4);
      #pragma unroll
      for (int td = 0; td < 4; ++td) {
        accA[td] = mfma16(va[td][ks], pfA, accA[td]);
        accB[td] = mfma16(va[td][ks], pfB, accB[td]);
      }
    }
    __builtin_amdgcn_s_setprio(0);
    d0A -= 64.0f; d0B -= 64.0f;
  }

  float invA = 1.0f / ssumA;
  float invB = 1.0f / ssumB;
  short* opA = O + (size_t)(b * SEQ + q0 + l15) * DM + h * DHD;
  short* opB = opA + (size_t)16 * DM;
  #pragma unroll
  for (int td = 0; td < 4; ++td) {
    uint2 wvA = { cvtpk(accA[td][0] * invA, accA[td][1] * invA),
                  cvtpk(accA[td][2] * invA, accA[td][3] * invA) };
    *reinterpret_cast<uint2*>(opA + td * 16 + lg * 4) = wvA;
    uint2 wvB = { cvtpk(accB[td][0] * invB, accB[td][1] * invB),
                  cvtpk(accB[td][2] * invB, accB[td][3] * invB) };
    *reinterpret_cast<uint2*>(opB + td * 16 + lg * 4) = wvB;
  }
}

extern "C" void kernel_launch(void* const* d_in, const int* in_sizes, int n_in,
                              void* d_out, int out_size, void* d_ws, size_t ws_size,
                              hipStream_t stream) {
  const float* x  = (const float*)d_in[0];
  const float* Wq = (const float*)d_in[1];
  const float* bq = (const float*)d_in[2];
  const float* Wk = (const float*)d_in[3];
  const float* bk = (const float*)d_in[4];
  const float* Wv = (const float*)d_in[5];
  const float* bv = (const float*)d_in[6];
  const float* Wo = (const float*)d_in[7];
  const float* bo = (const float*)d_in[8];
  const int*   pm = (const int*)d_in[9];

  char* ws = (char*)d_ws;
  const size_t MB = 1ull << 20;
  short* xb  = (short*)(ws + 0 * MB);
  short* q   = (short*)(ws + 16 * MB);
  short* kf  = (short*)(ws + 32 * MB);   // K' fragment-ready
  short* vf  = (short*)(ws + 48 * MB);   // V' fragment-ready
  short* ob  = (short*)(ws + 64 * MB);
  short* wqt = (short*)(ws + 80 * MB);
  short* wkt = (short*)(ws + 82 * MB);
  short* wvt = (short*)(ws + 84 * MB);
  short* wot = (short*)(ws + 86 * MB);
  float* fbias = (float*)(ws + 88 * MB);

  k_cast<<<dim3(MTOT * DM / 8 / 256), dim3(256), 0, stream>>>(x, xb, MTOT * DM);
  k_maskbias<<<dim3(MTOT / 256), dim3(256), 0, stream>>>(pm, fbias, MTOT);
  k_transpose<<<dim3(32, 32), dim3(32, 8), 0, stream>>>(Wq, wqt);
  k_transpose<<<dim3(32, 32), dim3(32, 8), 0, stream>>>(Wk, wkt);
  k_transpose<<<dim3(32, 32), dim3(32, 8), 0, stream>>>(Wv, wvt);
  k_transpose<<<dim3(32, 32), dim3(32, 8), 0, stream>>>(Wo, wot);
  // Q pre-scaled by log2e/8 (log2-domain softmax)
  k_gemm<0><<<dim3(64, 8), dim3(256), 0, stream>>>(xb, wqt, bq, q, 0.125f * 1.44269504f);
  k_gemm<3><<<dim3(64, 8), dim3(256), 0, stream>>>(xb, wkt, bk, kf, 1.0f);
  k_gemm<1><<<dim3(64, 8), dim3(256), 0, stream>>>(xb, wvt, bv, vf, 1.0f);
  k_attn<<<dim3(SEQ / 32 * NB * NH), dim3(64), 0, stream>>>(q, kf, vf, fbias, ob);
  k_gemm<2><<<dim3(64, 8), dim3(256), 0, stream>>>(ob, wot, bo, d_out, 1.0f);
}